// Round 10
// baseline (1525.215 us; speedup 1.0000x reference)
//
#include <hip/hip_runtime.h>
#include <hip/hip_bf16.h>
#include <stdint.h>

// FLGNN round 10: k_gemm3 gets double-buffered B staging (one barrier per
// rule, staging overlapped with MFMA); BN-stats folded into k_agg epilogue
// (k_bnstats eliminated). CSR radix build / in_mfma / head unchanged from r9.

#define NN 32768
#define NE 1048576
#define H 128
#define R 16
#define NL 3
#define ODIM 40
#define NBIN 64
#define BINCAP 18432

typedef short bf16x8 __attribute__((ext_vector_type(8)));
typedef float f32x4 __attribute__((ext_vector_type(4)));
typedef unsigned short u16x4 __attribute__((ext_vector_type(4)));

__device__ inline short f2bf_rne(float f) {
    unsigned u = __float_as_uint(f);
    u += 0x7FFFu + ((u >> 16) & 1u);
    return (short)(u >> 16);
}
__device__ inline void split_bf(float v, short& hi, short& lo) {
    unsigned u = __float_as_uint(v);
    unsigned uh = (u + 0x7FFFu + ((u >> 16) & 1u)) & 0xFFFF0000u;
    hi = (short)(uh >> 16);
    lo = f2bf_rne(v - __uint_as_float(uh));
}
__device__ inline f32x4 bf4f(u16x4 v) {
    f32x4 r;
    r.x = __uint_as_float((unsigned)v.x << 16);
    r.y = __uint_as_float((unsigned)v.y << 16);
    r.z = __uint_as_float((unsigned)v.z << 16);
    r.w = __uint_as_float((unsigned)v.w << 16);
    return r;
}
__device__ inline void gload_lds16(const void* g, void* l) {
    __builtin_amdgcn_global_load_lds(
        (const __attribute__((address_space(1))) unsigned*)g,
        (__attribute__((address_space(3))) unsigned*)l, 16, 0, 0);
}

__device__ inline f32x4 bn4(f32x4 hv, f32x4 av, f32x4 s1, f32x4 s2, f32x4 gm,
                            f32x4 bt) {
    f32x4 r;
#define BN_C(X)                                               \
    {                                                         \
        float mu = s1.X * (1.0f / NN);                        \
        float var = s2.X * (1.0f / NN) - mu * mu;             \
        float inv = rsqrtf(var + 1e-5f);                      \
        r.X = hv.X + (av.X - mu) * inv * gm.X + bt.X;         \
    }
    BN_C(x) BN_C(y) BN_C(z) BN_C(w)
#undef BN_C
    return r;
}

// ---------------- fused weight prep (cvtB + cvtW + cvtH + IW + binCnt=0) ---
__global__ __launch_bounds__(256) void k_prep_all(
    const float* __restrict__ Wc, short* __restrict__ WcT,
    const float* __restrict__ W_in, short* __restrict__ WinHi,
    short* __restrict__ WinLo, const float* __restrict__ W_head,
    short* __restrict__ WhHi, short* __restrict__ WhLo,
    const float* __restrict__ widths, float* __restrict__ IW,
    int* __restrict__ binCnt) {
    int bid = blockIdx.x, tid = threadIdx.x;
    if (bid < 3072) {  // Wc[l,r][k][o] -> bf16 swizzled [l,r][o][k]
        int s = bid * 256 + tid;
        int lr = s >> 14;
        int rem = s & 16383;
        int k = rem >> 7, o = rem & 127;
        int kb = k >> 3;
        int d = lr * 16384 + o * 128 + (((kb ^ (o & 7)) << 3)) + (k & 7);
        WcT[d] = f2bf_rne(Wc[s]);
    } else if (bid < 3136) {  // W_in hi/lo swizzled
        int t = (bid - 3072) * 256 + tid;
        int k = t >> 7, o = t & 127;
        int kb = k >> 3;
        int d = o * 128 + (((kb ^ (o & 7)) << 3)) + (k & 7);
        short hi, lo;
        split_bf(W_in[k * 128 + o], hi, lo);
        WinHi[d] = hi;
        WinLo[d] = lo;
    } else if (bid < 3160) {  // W_head padded to 48 cols, hi/lo swizzled
        int t = (bid - 3136) * 256 + tid;
        int o = t >> 7, k = t & 127;
        float v = (o < ODIM) ? W_head[k * ODIM + o] : 0.0f;
        int kb = k >> 3;
        int d = o * 128 + (((kb ^ (o & 7)) << 3)) + (k & 7);
        short hi, lo;
        split_bf(v, hi, lo);
        WhHi[d] = hi;
        WhLo[d] = lo;
    } else if (bid < 3184) {  // IW = 0.5/(w^2*128)
        int t = (bid - 3160) * 256 + tid;
        float wd = widths[t];
        IW[t] = 0.5f / (wd * wd) * (1.0f / 128.0f);
    } else {  // zero bin counters
        if (tid < NBIN) binCnt[tid] = 0;
    }
}

// ------- pass 1: partition edges into 64 coarse bins (dst>>9) --------------
__global__ __launch_bounds__(256) void k_part(const int* __restrict__ src,
                                              const int* __restrict__ dst,
                                              int* __restrict__ binCnt,
                                              int* __restrict__ pbuf) {
    __shared__ int hist[NBIN];
    int tid = threadIdx.x;
    int e0 = blockIdx.x * 8192;
    if (tid < NBIN) hist[tid] = 0;
    __syncthreads();
    for (int i = tid; i < 8192; i += 256)
        atomicAdd(&hist[dst[e0 + i] >> 9], 1);
    __syncthreads();
    if (tid < NBIN) hist[tid] = atomicAdd(&binCnt[tid], hist[tid]);
    __syncthreads();
    for (int i = tid; i < 8192; i += 256) {
        int d = dst[e0 + i], s = src[e0 + i];
        int b = d >> 9;
        int p = atomicAdd(&hist[b], 1);
        pbuf[b * BINCAP + p] = s | ((d & 511) << 15);
    }
}

// ------- scan of 64 bin counts (one wave); also zeroes BN sums -------------
__global__ __launch_bounds__(64) void k_scan64(const int* __restrict__ binCnt,
                                               int* __restrict__ binStart,
                                               int* __restrict__ row_start,
                                               float* __restrict__ sumsAll) {
    int t = threadIdx.x;
    for (int i = t; i < 768; i += 64) sumsAll[i] = 0.0f;
    int c = binCnt[t];
    int v = c;
    for (int off = 1; off < 64; off <<= 1) {
        int u = __shfl_up(v, off);
        if (t >= off) v += u;
    }
    binStart[t] = v - c;
    if (t == 63) {
        binStart[NBIN] = v;
        row_start[NN] = v;  // == NE
    }
}

// ------- pass 2: per-bin counting sort -> per-node CSR ---------------------
__global__ __launch_bounds__(512) void k_sortp(const int* __restrict__ binCnt,
                                               const int* __restrict__ binStart,
                                               const int* __restrict__ pbuf,
                                               int* __restrict__ esrc,
                                               int* __restrict__ row_start) {
    __shared__ int cnt[512], sc[512], cur[512];
    int b = blockIdx.x, t = threadIdx.x;
    int n = binCnt[b];
    int gbase = binStart[b];
    const int* p = pbuf + b * BINCAP;
    cnt[t] = 0;
    __syncthreads();
    for (int i = t; i < n; i += 512)
        atomicAdd(&cnt[(p[i] >> 15) & 511], 1);
    __syncthreads();
    sc[t] = cnt[t];
    __syncthreads();
    for (int off = 1; off < 512; off <<= 1) {
        int v = (t >= off) ? sc[t - off] : 0;
        __syncthreads();
        sc[t] += v;
        __syncthreads();
    }
    int start = gbase + sc[t] - cnt[t];
    row_start[b * 512 + t] = start;
    cur[t] = start;
    __syncthreads();
    for (int i = t; i < n; i += 512) {
        int e = p[i];
        int pos = atomicAdd(&cur[(e >> 15) & 511], 1);
        esrc[pos] = e & 32767;
    }
}

// ---------------- input layer via MFMA: h = relu(x @ W_in + b_in) ----------
__global__ __launch_bounds__(256, 2) void k_in_mfma(
    const float* __restrict__ x, const short* __restrict__ Whi,
    const short* __restrict__ Wlo, const float* __restrict__ b,
    float* __restrict__ h) {
    __shared__ short Bs[16384];
    int tid = threadIdx.x, lane = tid & 63, wv = tid >> 6;
    int quad = lane >> 4, lm = lane & 15;
    int row0 = blockIdx.x * 64;
    int m = row0 + wv * 16 + lm;

    bf16x8 ahi[4], alo[4];
#pragma unroll
    for (int kc = 0; kc < 4; kc++) {
        f32x4 va = *(const f32x4*)(x + m * H + kc * 32 + quad * 8);
        f32x4 vb = *(const f32x4*)(x + m * H + kc * 32 + quad * 8 + 4);
        float vv[8] = {va.x, va.y, va.z, va.w, vb.x, vb.y, vb.z, vb.w};
#pragma unroll
        for (int j = 0; j < 8; j++) {
            short hi, lo;
            split_bf(vv[j], hi, lo);
            ahi[kc][j] = hi;
            alo[kc][j] = lo;
        }
    }
    f32x4 acc[8];
#pragma unroll
    for (int c = 0; c < 8; c++) acc[c] = (f32x4){0.f, 0.f, 0.f, 0.f};

    char* ldst = (char*)Bs + wv * 8192;
    const char* g1 = (const char*)Whi + wv * 8192 + lane * 16;
#pragma unroll
    for (int cc = 0; cc < 8; cc++) gload_lds16(g1 + cc * 1024, ldst + cc * 1024);
    __syncthreads();
#pragma unroll
    for (int kc = 0; kc < 4; kc++)
#pragma unroll
        for (int c = 0; c < 8; c++) {
            int o = c * 16 + lm;
            bf16x8 bfr = *(const bf16x8*)&Bs[o * 128 + (((kc * 4 + quad) ^ (o & 7)) << 3)];
            acc[c] = __builtin_amdgcn_mfma_f32_16x16x32_bf16(ahi[kc], bfr, acc[c], 0, 0, 0);
            acc[c] = __builtin_amdgcn_mfma_f32_16x16x32_bf16(alo[kc], bfr, acc[c], 0, 0, 0);
        }
    __syncthreads();
    const char* g2 = (const char*)Wlo + wv * 8192 + lane * 16;
#pragma unroll
    for (int cc = 0; cc < 8; cc++) gload_lds16(g2 + cc * 1024, ldst + cc * 1024);
    __syncthreads();
#pragma unroll
    for (int kc = 0; kc < 4; kc++)
#pragma unroll
        for (int c = 0; c < 8; c++) {
            int o = c * 16 + lm;
            bf16x8 bfr = *(const bf16x8*)&Bs[o * 128 + (((kc * 4 + quad) ^ (o & 7)) << 3)];
            acc[c] = __builtin_amdgcn_mfma_f32_16x16x32_bf16(ahi[kc], bfr, acc[c], 0, 0, 0);
        }
    int orow = row0 + wv * 16 + quad * 4;
#pragma unroll
    for (int c = 0; c < 8; c++) {
        int col = c * 16 + lm;
        float bi = b[col];
#pragma unroll
        for (int v = 0; v < 4; v++)
            h[(orow + v) * H + col] = fmaxf(acc[c][v] + bi, 0.0f);
    }
}

// ------- fused BN+residual + memberships + rule-mix GEMM (BM=64) -----------
// Double-buffered B staging: one barrier per rule; rule r+1 staged while
// computing rule r. hs prologue overlays the 64 KB dbuf region (dead after
// fragment extraction).
__global__ __launch_bounds__(256, 2) void k_gemm3(
    const float* __restrict__ h, const float* __restrict__ aprev,
    const float* __restrict__ sums, const float* __restrict__ gamma,
    const float* __restrict__ beta, const short* __restrict__ BT,
    const float* __restrict__ bc, const float* __restrict__ cen,
    const float* __restrict__ iw, unsigned short* __restrict__ msgb,
    float* __restrict__ hout) {
    __shared__ __align__(16) char smem[65536];  // Bs[2][16384] shorts; hs overlay
    float(*hs)[132] = (float(*)[132])smem;      // 33792 B, prologue only
    __shared__ float wsh[16][64];
    __shared__ float sm[64][17];

    int tid = threadIdx.x, lane = tid & 63, wv = tid >> 6;
    int quad = lane >> 4, lm = lane & 15;
    int row0 = blockIdx.x * 64;

    // stage h tile (64x128 f32); BN+residual fusion when gamma != null
    if (gamma) {
        for (int g = tid; g < 2048; g += 256) {
            int rr = g >> 5, cc = (g & 31) << 2;
            int grow = row0 + rr;
            f32x4 hv = *(const f32x4*)&h[grow * H + cc];
            f32x4 av = *(const f32x4*)&aprev[grow * H + cc];
            f32x4 r = bn4(hv, av, *(const f32x4*)&sums[cc],
                          *(const f32x4*)&sums[H + cc],
                          *(const f32x4*)&gamma[cc], *(const f32x4*)&beta[cc]);
            *(f32x4*)&hs[rr][cc] = r;
            *(f32x4*)&hout[grow * H + cc] = r;
        }
    } else {
        const f32x4* hg = (const f32x4*)(h + row0 * H);
        for (int g = tid; g < 2048; g += 256) {
            int rr = g >> 5, cc = (g & 31) << 2;
            *(f32x4*)&hs[rr][cc] = hg[g];
        }
    }
    __syncthreads();

    // membership partial scores: wave wv -> rules wv*4..+3, lane = row
    {
        int wvu = __builtin_amdgcn_readfirstlane(wv);
        const float* c0 = cen + (wvu * 4 + 0) * H;
        const float* c1 = cen + (wvu * 4 + 1) * H;
        const float* c2 = cen + (wvu * 4 + 2) * H;
        const float* c3 = cen + (wvu * 4 + 3) * H;
        const float* w0 = iw + (wvu * 4 + 0) * H;
        const float* w1 = iw + (wvu * 4 + 1) * H;
        const float* w2 = iw + (wvu * 4 + 2) * H;
        const float* w3 = iw + (wvu * 4 + 3) * H;
        float s0 = 0.f, s1 = 0.f, s2 = 0.f, s3 = 0.f;
#pragma unroll 4
        for (int j0 = 0; j0 < H; j0 += 4) {
            f32x4 hv = *(const f32x4*)&hs[lane][j0];
            f32x4 cv, wv4, d;
            cv = *(const f32x4*)(c0 + j0); wv4 = *(const f32x4*)(w0 + j0);
            d = hv - cv;
            s0 += d.x * d.x * wv4.x + d.y * d.y * wv4.y + d.z * d.z * wv4.z + d.w * d.w * wv4.w;
            cv = *(const f32x4*)(c1 + j0); wv4 = *(const f32x4*)(w1 + j0);
            d = hv - cv;
            s1 += d.x * d.x * wv4.x + d.y * d.y * wv4.y + d.z * d.z * wv4.z + d.w * d.w * wv4.w;
            cv = *(const f32x4*)(c2 + j0); wv4 = *(const f32x4*)(w2 + j0);
            d = hv - cv;
            s2 += d.x * d.x * wv4.x + d.y * d.y * wv4.y + d.z * d.z * wv4.z + d.w * d.w * wv4.w;
            cv = *(const f32x4*)(c3 + j0); wv4 = *(const f32x4*)(w3 + j0);
            d = hv - cv;
            s3 += d.x * d.x * wv4.x + d.y * d.y * wv4.y + d.z * d.z * wv4.z + d.w * d.w * wv4.w;
        }
        sm[lane][wvu * 4 + 0] = s0;
        sm[lane][wvu * 4 + 1] = s1;
        sm[lane][wvu * 4 + 2] = s2;
        sm[lane][wvu * 4 + 3] = s3;
    }

    // extract this lane's A-row fragments (hi/lo split), from LDS
    bf16x8 ahi[4], alo[4];
    {
        int m = wv * 16 + lm;
#pragma unroll
        for (int kc = 0; kc < 4; kc++) {
            f32x4 va = *(const f32x4*)&hs[m][kc * 32 + quad * 8];
            f32x4 vb = *(const f32x4*)&hs[m][kc * 32 + quad * 8 + 4];
            float vv[8] = {va.x, va.y, va.z, va.w, vb.x, vb.y, vb.z, vb.w};
#pragma unroll
            for (int j = 0; j < 8; j++) {
                short hi, lo;
                split_bf(vv[j], hi, lo);
                ahi[kc][j] = hi;
                alo[kc][j] = lo;
            }
        }
    }
    __syncthreads();  // hs consumers done -> dbuf region free

    // softmax over 16 rules per row -> wsh[r][row]
    if (tid < 64) {
        float v[16], mx = -1e30f;
#pragma unroll
        for (int r = 0; r < R; r++) {
            v[r] = -sm[tid][r];
            mx = fmaxf(mx, v[r]);
        }
        float sum = 0.f, e[16];
#pragma unroll
        for (int r = 0; r < R; r++) {
            e[r] = __expf(v[r] - mx);
            sum += e[r];
        }
        float inv = 1.0f / sum;
#pragma unroll
        for (int r = 0; r < R; r++) wsh[r][tid] = e[r] * inv;
    }

    // prologue: stage rule 0 into half 0
    {
        const char* gsrc = (const char*)BT + wv * 8192 + lane * 16;
        char* ld = smem + wv * 8192;
#pragma unroll
        for (int cc = 0; cc < 8; cc++) gload_lds16(gsrc + cc * 1024, ld + cc * 1024);
    }
    __syncthreads();  // wsh visible + rule0 staged

    f32x4 out[8];
#pragma unroll
    for (int c = 0; c < 8; c++) out[c] = (f32x4){0.f, 0.f, 0.f, 0.f};

    for (int r = 0; r < R; r++) {
        // prefetch rule r+1 into the other half (async, overlaps compute)
        if (r + 1 < R) {
            const char* gsrc = (const char*)(BT + (r + 1) * 16384) + wv * 8192 + lane * 16;
            char* ld = smem + ((r + 1) & 1) * 32768 + wv * 8192;
#pragma unroll
            for (int cc = 0; cc < 8; cc++)
                gload_lds16(gsrc + cc * 1024, ld + cc * 1024);
        }
        const short* Bcur = (const short*)(smem + (r & 1) * 32768);

        f32x4 accr[8];
#pragma unroll
        for (int c = 0; c < 8; c++) accr[c] = (f32x4){0.f, 0.f, 0.f, 0.f};
#pragma unroll
        for (int kc = 0; kc < 4; kc++)
#pragma unroll
            for (int c = 0; c < 8; c++) {
                int o = c * 16 + lm;
                bf16x8 bfr = *(const bf16x8*)&Bcur[o * 128 + (((kc * 4 + quad) ^ (o & 7)) << 3)];
                accr[c] = __builtin_amdgcn_mfma_f32_16x16x32_bf16(ahi[kc], bfr, accr[c], 0, 0, 0);
                accr[c] = __builtin_amdgcn_mfma_f32_16x16x32_bf16(alo[kc], bfr, accr[c], 0, 0, 0);
            }
        f32x4 wr4 = *(const f32x4*)&wsh[r][wv * 16 + quad * 4];
#pragma unroll
        for (int c = 0; c < 8; c++) {
            out[c].x += wr4.x * accr[c].x;
            out[c].y += wr4.y * accr[c].y;
            out[c].z += wr4.z * accr[c].z;
            out[c].w += wr4.w * accr[c].w;
        }
        __syncthreads();  // drains prefetch vmcnt + syncs consumers
    }

    // bias via one K=32 MFMA: A = w (k<16 else 0), B = bc (staged into half 0)
    short* Bs0 = (short*)smem;
    for (int g = tid; g < 512; g += 256) {
        int o = g >> 2, kb = g & 3;
        bf16x8 v;
#pragma unroll
        for (int j = 0; j < 8; j++) {
            int k = kb * 8 + j;
            v[j] = (k < R) ? f2bf_rne(bc[k * H + o]) : (short)0;
        }
        *(bf16x8*)&Bs0[o * 128 + ((kb ^ (o & 7)) << 3)] = v;
    }
    bf16x8 abias;
#pragma unroll
    for (int j = 0; j < 8; j++)
        abias[j] = (quad < 2) ? f2bf_rne(wsh[quad * 8 + j][wv * 16 + lm]) : (short)0;
    __syncthreads();
#pragma unroll
    for (int c = 0; c < 8; c++) {
        int o = c * 16 + lm;
        bf16x8 bfr = *(const bf16x8*)&Bs0[o * 128 + ((quad ^ (o & 7)) << 3)];
        out[c] = __builtin_amdgcn_mfma_f32_16x16x32_bf16(abias, bfr, out[c], 0, 0, 0);
    }

    // store msg as bf16
    int orow = row0 + wv * 16 + quad * 4;
#pragma unroll
    for (int c = 0; c < 8; c++) {
        int col = c * 16 + lm;
#pragma unroll
        for (int v = 0; v < 4; v++)
            msgb[(orow + v) * H + col] = (unsigned short)f2bf_rne(out[c][v]);
    }
}

// ---------- CSR aggregate (8-deep ILP) + fused relu/mean/BN-stats ----------
__global__ __launch_bounds__(256) void k_agg(
    const unsigned short* __restrict__ msgb, const int* __restrict__ row_start,
    const int* __restrict__ esrc, float* __restrict__ a,
    float* __restrict__ sums) {
    __shared__ f32x4 red1[8][32];
    __shared__ f32x4 red2[8][32];
    int tid = threadIdx.x;
    int g = tid >> 5, lane = tid & 31;
    int n = blockIdx.x * 8 + g;
    int b = row_start[n], e = row_start[n + 1];
    f32x4 a0 = {0.f, 0.f, 0.f, 0.f}, a1 = a0, a2 = a0, a3 = a0;
    f32x4 a4 = a0, a5 = a0, a6 = a0, a7 = a0;
    int i = b;
    for (; i + 8 <= e; i += 8) {
        int s0 = esrc[i], s1 = esrc[i + 1], s2 = esrc[i + 2], s3 = esrc[i + 3];
        int s4 = esrc[i + 4], s5 = esrc[i + 5], s6 = esrc[i + 6], s7 = esrc[i + 7];
        a0 += bf4f(*(const u16x4*)&msgb[s0 * H + lane * 4]);
        a1 += bf4f(*(const u16x4*)&msgb[s1 * H + lane * 4]);
        a2 += bf4f(*(const u16x4*)&msgb[s2 * H + lane * 4]);
        a3 += bf4f(*(const u16x4*)&msgb[s3 * H + lane * 4]);
        a4 += bf4f(*(const u16x4*)&msgb[s4 * H + lane * 4]);
        a5 += bf4f(*(const u16x4*)&msgb[s5 * H + lane * 4]);
        a6 += bf4f(*(const u16x4*)&msgb[s6 * H + lane * 4]);
        a7 += bf4f(*(const u16x4*)&msgb[s7 * H + lane * 4]);
    }
    for (; i < e; i++)
        a0 += bf4f(*(const u16x4*)&msgb[esrc[i] * H + lane * 4]);
    f32x4 t = ((a0 + a1) + (a2 + a3)) + ((a4 + a5) + (a6 + a7));
    float id = 1.0f / fmaxf((float)(e - b), 1.0f);
    f32x4 res;
    res.x = fmaxf(t.x * id, 0.f);
    res.y = fmaxf(t.y * id, 0.f);
    res.z = fmaxf(t.z * id, 0.f);
    res.w = fmaxf(t.w * id, 0.f);
    *(f32x4*)&a[n * H + lane * 4] = res;
    // fused BN stats: per-block reduce over the 8 nodes, then 256 atomics
    red1[g][lane] = res;
    f32x4 r2 = {res.x * res.x, res.y * res.y, res.z * res.z, res.w * res.w};
    red2[g][lane] = r2;
    __syncthreads();
    int c0 = lane * 4;
    if (g == 0) {
        f32x4 t1 = red1[0][lane];
#pragma unroll
        for (int gg = 1; gg < 8; gg++) t1 += red1[gg][lane];
        atomicAdd(&sums[c0], t1.x);
        atomicAdd(&sums[c0 + 1], t1.y);
        atomicAdd(&sums[c0 + 2], t1.z);
        atomicAdd(&sums[c0 + 3], t1.w);
    } else if (g == 1) {
        f32x4 t2 = red2[0][lane];
#pragma unroll
        for (int gg = 1; gg < 8; gg++) t2 += red2[gg][lane];
        atomicAdd(&sums[H + c0], t2.x);
        atomicAdd(&sums[H + c0 + 1], t2.y);
        atomicAdd(&sums[H + c0 + 2], t2.z);
        atomicAdd(&sums[H + c0 + 3], t2.w);
    }
}

// ---------------- head: fused BN+residual -> MFMA -> softmax ----------------
__global__ __launch_bounds__(256, 2) void k_head2(
    const float* __restrict__ h, const float* __restrict__ aprev,
    const float* __restrict__ sums, const float* __restrict__ gamma,
    const float* __restrict__ beta, const short* __restrict__ Whi,
    const short* __restrict__ Wlo, const float* __restrict__ bh,
    float* __restrict__ out) {
    __shared__ short Bs[12288];  // hi: shorts [0,6144), lo: shorts [6144,12288)
    int tid = threadIdx.x, lane = tid & 63, wv = tid >> 6;
    int quad = lane >> 4, lm = lane & 15;
    int row0 = blockIdx.x * 64;
    int m = row0 + wv * 16 + lm;

    bf16x8 ahi[4], alo[4];
#pragma unroll
    for (int kc = 0; kc < 4; kc++) {
        int base = kc * 32 + quad * 8;
        f32x4 hv0 = *(const f32x4*)&h[m * H + base];
        f32x4 hv1 = *(const f32x4*)&h[m * H + base + 4];
        f32x4 av0 = *(const f32x4*)&aprev[m * H + base];
        f32x4 av1 = *(const f32x4*)&aprev[m * H + base + 4];
        f32x4 r0 = bn4(hv0, av0, *(const f32x4*)&sums[base],
                       *(const f32x4*)&sums[H + base],
                       *(const f32x4*)&gamma[base], *(const f32x4*)&beta[base]);
        f32x4 r1 = bn4(hv1, av1, *(const f32x4*)&sums[base + 4],
                       *(const f32x4*)&sums[H + base + 4],
                       *(const f32x4*)&gamma[base + 4],
                       *(const f32x4*)&beta[base + 4]);
        float vv[8] = {r0.x, r0.y, r0.z, r0.w, r1.x, r1.y, r1.z, r1.w};
#pragma unroll
        for (int j = 0; j < 8; j++) {
            short hi, lo;
            split_bf(vv[j], hi, lo);
            ahi[kc][j] = hi;
            alo[kc][j] = lo;
        }
    }
    {
        char* ldst = (char*)Bs + wv * 3072;
        const char* g1 = (const char*)Whi + wv * 3072 + lane * 16;
        const char* g2 = (const char*)Wlo + wv * 3072 + lane * 16;
#pragma unroll
        for (int cc = 0; cc < 3; cc++) gload_lds16(g1 + cc * 1024, ldst + cc * 1024);
        char* ldst2 = (char*)Bs + 12288 + wv * 3072;  // byte offset of lo half
#pragma unroll
        for (int cc = 0; cc < 3; cc++) gload_lds16(g2 + cc * 1024, ldst2 + cc * 1024);
    }
    __syncthreads();
    f32x4 acc[3];
#pragma unroll
    for (int c = 0; c < 3; c++) acc[c] = (f32x4){0.f, 0.f, 0.f, 0.f};
#pragma unroll
    for (int kc = 0; kc < 4; kc++)
#pragma unroll
        for (int c = 0; c < 3; c++) {
            int o = c * 16 + lm;
            int off = o * 128 + (((kc * 4 + quad) ^ (o & 7)) << 3);
            bf16x8 bH = *(const bf16x8*)&Bs[off];
            bf16x8 bL = *(const bf16x8*)&Bs[6144 + off];
            acc[c] = __builtin_amdgcn_mfma_f32_16x16x32_bf16(ahi[kc], bH, acc[c], 0, 0, 0);
            acc[c] = __builtin_amdgcn_mfma_f32_16x16x32_bf16(alo[kc], bH, acc[c], 0, 0, 0);
            acc[c] = __builtin_amdgcn_mfma_f32_16x16x32_bf16(ahi[kc], bL, acc[c], 0, 0, 0);
        }
    float bh0 = bh[lm], bh1 = bh[16 + lm];
    float bh2 = (lm < 8) ? bh[32 + lm] : 0.f;
    int orow = row0 + wv * 16 + quad * 4;
#pragma unroll
    for (int v = 0; v < 4; v++) {
        float v0 = acc[0][v] + bh0;
        float v1 = acc[1][v] + bh1;
        float v2 = (lm < 8) ? (acc[2][v] + bh2) : -1e30f;
        float mx = fmaxf(fmaxf(v0, v1), v2);
        for (int off = 8; off; off >>= 1) mx = fmaxf(mx, __shfl_xor(mx, off, 16));
        float e0 = __expf(v0 - mx), e1 = __expf(v1 - mx);
        float e2 = (lm < 8) ? __expf(v2 - mx) : 0.f;
        float s = e0 + e1 + e2;
        for (int off = 8; off; off >>= 1) s += __shfl_xor(s, off, 16);
        float inv = 1.0f / s;
        out[(orow + v) * ODIM + lm] = e0 * inv;
        out[(orow + v) * ODIM + 16 + lm] = e1 * inv;
        if (lm < 8) out[(orow + v) * ODIM + 32 + lm] = e2 * inv;
    }
}

extern "C" void kernel_launch(void* const* d_in, const int* in_sizes, int n_in,
                              void* d_out, int out_size, void* d_ws, size_t ws_size,
                              hipStream_t stream) {
    const float* x = (const float*)d_in[0];
    const int* edge_index = (const int*)d_in[1];
    const float* W_in = (const float*)d_in[2];
    const float* b_in = (const float*)d_in[3];
    const float* centers = (const float*)d_in[4];
    const float* widths = (const float*)d_in[5];
    const float* Wc = (const float*)d_in[6];
    const float* bc = (const float*)d_in[7];
    const float* bn_gamma = (const float*)d_in[8];
    const float* bn_beta = (const float*)d_in[9];
    const float* W_head = (const float*)d_in[10];
    const float* b_head = (const float*)d_in[11];
    float* out = (float*)d_out;

    const int* src = edge_index;
    const int* dst = edge_index + NE;

    // workspace layout
    float* h = (float*)d_ws;
    float* a = h + NN * H;
    float* sumsAll = a + NN * H;      // 3 x 256
    float* IW = sumsAll + 768;        // NL*R*H
    int* binCnt = (int*)(IW + NL * R * H);  // 64
    int* binStart = binCnt + NBIN;    // 65
    int* row_start = binStart + NBIN + 1;   // NN+1
    int* pbuf = row_start + NN + 1;   // NBIN*BINCAP
    int* esrc = pbuf + NBIN * BINCAP; // NE
    uintptr_t p = (uintptr_t)(esrc + NE);
    p = (p + 63) & ~(uintptr_t)63;
    unsigned short* msgb = (unsigned short*)p;  // NN*H bf16
    short* WcT = (short*)(msgb + NN * H);       // NL*R*H*H
    short* WinHi = WcT + NL * R * H * H;        // 16384
    short* WinLo = WinHi + 16384;
    short* WhHi = WinLo + 16384;                // 6144
    short* WhLo = WhHi + 6144;

    k_prep_all<<<3185, 256, 0, stream>>>(Wc, WcT, W_in, WinHi, WinLo, W_head,
                                         WhHi, WhLo, widths, IW, binCnt);
    k_part<<<NE / 8192, 256, 0, stream>>>(src, dst, binCnt, pbuf);
    k_scan64<<<1, 64, 0, stream>>>(binCnt, binStart, row_start, sumsAll);
    k_sortp<<<NBIN, 512, 0, stream>>>(binCnt, binStart, pbuf, esrc, row_start);

    k_in_mfma<<<NN / 64, 256, 0, stream>>>(x, WinHi, WinLo, b_in, h);

    for (int l = 0; l < NL; l++) {
        const float* gm = (l == 0) ? nullptr : bn_gamma + (l - 1) * H;
        const float* bt = (l == 0) ? nullptr : bn_beta + (l - 1) * H;
        const float* sm = (l == 0) ? nullptr : sumsAll + 256 * (l - 1);
        k_gemm3<<<NN / 64, 256, 0, stream>>>(h, a, sm, gm, bt,
                                             WcT + l * R * H * H, bc + l * R * H,
                                             centers + l * R * H, IW + l * R * H,
                                             msgb, h);
        k_agg<<<NN / 8, 256, 0, stream>>>(msgb, row_start, esrc, a,
                                          sumsAll + 256 * l);
    }
    k_head2<<<NN / 64, 256, 0, stream>>>(h, a, sumsAll + 512, bn_gamma + 2 * H,
                                         bn_beta + 2 * H, WhHi, WhLo, b_head, out);
}

// Round 11
// 498.268 us; speedup vs baseline: 3.0610x; 3.0610x over previous
//
#include <hip/hip_runtime.h>
#include <hip/hip_bf16.h>
#include <stdint.h>

// FLGNN round 11: r9 structure + r10's double-buffered gemm (kept: ~37 vs 57
// us) + r9's plain k_agg (r10's fused BN-stats epilogue caused 1M contended
// atomics onto 256 addresses -> 408 us; reverted) + separate k_bnstats (512
// shallow atomic chains, hidden under its own 16 MB read).

#define NN 32768
#define NE 1048576
#define H 128
#define R 16
#define NL 3
#define ODIM 40
#define NBIN 64
#define BINCAP 18432

typedef short bf16x8 __attribute__((ext_vector_type(8)));
typedef float f32x4 __attribute__((ext_vector_type(4)));
typedef unsigned short u16x4 __attribute__((ext_vector_type(4)));

__device__ inline short f2bf_rne(float f) {
    unsigned u = __float_as_uint(f);
    u += 0x7FFFu + ((u >> 16) & 1u);
    return (short)(u >> 16);
}
__device__ inline void split_bf(float v, short& hi, short& lo) {
    unsigned u = __float_as_uint(v);
    unsigned uh = (u + 0x7FFFu + ((u >> 16) & 1u)) & 0xFFFF0000u;
    hi = (short)(uh >> 16);
    lo = f2bf_rne(v - __uint_as_float(uh));
}
__device__ inline f32x4 bf4f(u16x4 v) {
    f32x4 r;
    r.x = __uint_as_float((unsigned)v.x << 16);
    r.y = __uint_as_float((unsigned)v.y << 16);
    r.z = __uint_as_float((unsigned)v.z << 16);
    r.w = __uint_as_float((unsigned)v.w << 16);
    return r;
}
__device__ inline void gload_lds16(const void* g, void* l) {
    __builtin_amdgcn_global_load_lds(
        (const __attribute__((address_space(1))) unsigned*)g,
        (__attribute__((address_space(3))) unsigned*)l, 16, 0, 0);
}

__device__ inline f32x4 bn4(f32x4 hv, f32x4 av, f32x4 s1, f32x4 s2, f32x4 gm,
                            f32x4 bt) {
    f32x4 r;
#define BN_C(X)                                               \
    {                                                         \
        float mu = s1.X * (1.0f / NN);                        \
        float var = s2.X * (1.0f / NN) - mu * mu;             \
        float inv = rsqrtf(var + 1e-5f);                      \
        r.X = hv.X + (av.X - mu) * inv * gm.X + bt.X;         \
    }
    BN_C(x) BN_C(y) BN_C(z) BN_C(w)
#undef BN_C
    return r;
}

// ---------------- fused weight prep (cvtB + cvtW + cvtH + IW + binCnt=0) ---
__global__ __launch_bounds__(256) void k_prep_all(
    const float* __restrict__ Wc, short* __restrict__ WcT,
    const float* __restrict__ W_in, short* __restrict__ WinHi,
    short* __restrict__ WinLo, const float* __restrict__ W_head,
    short* __restrict__ WhHi, short* __restrict__ WhLo,
    const float* __restrict__ widths, float* __restrict__ IW,
    int* __restrict__ binCnt) {
    int bid = blockIdx.x, tid = threadIdx.x;
    if (bid < 3072) {  // Wc[l,r][k][o] -> bf16 swizzled [l,r][o][k]
        int s = bid * 256 + tid;
        int lr = s >> 14;
        int rem = s & 16383;
        int k = rem >> 7, o = rem & 127;
        int kb = k >> 3;
        int d = lr * 16384 + o * 128 + (((kb ^ (o & 7)) << 3)) + (k & 7);
        WcT[d] = f2bf_rne(Wc[s]);
    } else if (bid < 3136) {  // W_in hi/lo swizzled
        int t = (bid - 3072) * 256 + tid;
        int k = t >> 7, o = t & 127;
        int kb = k >> 3;
        int d = o * 128 + (((kb ^ (o & 7)) << 3)) + (k & 7);
        short hi, lo;
        split_bf(W_in[k * 128 + o], hi, lo);
        WinHi[d] = hi;
        WinLo[d] = lo;
    } else if (bid < 3160) {  // W_head padded to 48 cols, hi/lo swizzled
        int t = (bid - 3136) * 256 + tid;
        int o = t >> 7, k = t & 127;
        float v = (o < ODIM) ? W_head[k * ODIM + o] : 0.0f;
        int kb = k >> 3;
        int d = o * 128 + (((kb ^ (o & 7)) << 3)) + (k & 7);
        short hi, lo;
        split_bf(v, hi, lo);
        WhHi[d] = hi;
        WhLo[d] = lo;
    } else if (bid < 3184) {  // IW = 0.5/(w^2*128)
        int t = (bid - 3160) * 256 + tid;
        float wd = widths[t];
        IW[t] = 0.5f / (wd * wd) * (1.0f / 128.0f);
    } else {  // zero bin counters
        if (tid < NBIN) binCnt[tid] = 0;
    }
}

// ------- pass 1: partition edges into 64 coarse bins (dst>>9) --------------
__global__ __launch_bounds__(256) void k_part(const int* __restrict__ src,
                                              const int* __restrict__ dst,
                                              int* __restrict__ binCnt,
                                              int* __restrict__ pbuf) {
    __shared__ int hist[NBIN];
    int tid = threadIdx.x;
    int e0 = blockIdx.x * 8192;
    if (tid < NBIN) hist[tid] = 0;
    __syncthreads();
    for (int i = tid; i < 8192; i += 256)
        atomicAdd(&hist[dst[e0 + i] >> 9], 1);
    __syncthreads();
    if (tid < NBIN) hist[tid] = atomicAdd(&binCnt[tid], hist[tid]);
    __syncthreads();
    for (int i = tid; i < 8192; i += 256) {
        int d = dst[e0 + i], s = src[e0 + i];
        int b = d >> 9;
        int p = atomicAdd(&hist[b], 1);
        pbuf[b * BINCAP + p] = s | ((d & 511) << 15);
    }
}

// ------- scan of 64 bin counts (one wave); also zeroes BN sums -------------
__global__ __launch_bounds__(64) void k_scan64(const int* __restrict__ binCnt,
                                               int* __restrict__ binStart,
                                               int* __restrict__ row_start,
                                               float* __restrict__ sumsAll) {
    int t = threadIdx.x;
    for (int i = t; i < 768; i += 64) sumsAll[i] = 0.0f;
    int c = binCnt[t];
    int v = c;
    for (int off = 1; off < 64; off <<= 1) {
        int u = __shfl_up(v, off);
        if (t >= off) v += u;
    }
    binStart[t] = v - c;
    if (t == 63) {
        binStart[NBIN] = v;
        row_start[NN] = v;  // == NE
    }
}

// ------- pass 2: per-bin counting sort -> per-node CSR ---------------------
__global__ __launch_bounds__(512) void k_sortp(const int* __restrict__ binCnt,
                                               const int* __restrict__ binStart,
                                               const int* __restrict__ pbuf,
                                               int* __restrict__ esrc,
                                               int* __restrict__ row_start) {
    __shared__ int cnt[512], sc[512], cur[512];
    int b = blockIdx.x, t = threadIdx.x;
    int n = binCnt[b];
    int gbase = binStart[b];
    const int* p = pbuf + b * BINCAP;
    cnt[t] = 0;
    __syncthreads();
    for (int i = t; i < n; i += 512)
        atomicAdd(&cnt[(p[i] >> 15) & 511], 1);
    __syncthreads();
    sc[t] = cnt[t];
    __syncthreads();
    for (int off = 1; off < 512; off <<= 1) {
        int v = (t >= off) ? sc[t - off] : 0;
        __syncthreads();
        sc[t] += v;
        __syncthreads();
    }
    int start = gbase + sc[t] - cnt[t];
    row_start[b * 512 + t] = start;
    cur[t] = start;
    __syncthreads();
    for (int i = t; i < n; i += 512) {
        int e = p[i];
        int pos = atomicAdd(&cur[(e >> 15) & 511], 1);
        esrc[pos] = e & 32767;
    }
}

// ---------------- input layer via MFMA: h = relu(x @ W_in + b_in) ----------
__global__ __launch_bounds__(256, 2) void k_in_mfma(
    const float* __restrict__ x, const short* __restrict__ Whi,
    const short* __restrict__ Wlo, const float* __restrict__ b,
    float* __restrict__ h) {
    __shared__ short Bs[16384];
    int tid = threadIdx.x, lane = tid & 63, wv = tid >> 6;
    int quad = lane >> 4, lm = lane & 15;
    int row0 = blockIdx.x * 64;
    int m = row0 + wv * 16 + lm;

    bf16x8 ahi[4], alo[4];
#pragma unroll
    for (int kc = 0; kc < 4; kc++) {
        f32x4 va = *(const f32x4*)(x + m * H + kc * 32 + quad * 8);
        f32x4 vb = *(const f32x4*)(x + m * H + kc * 32 + quad * 8 + 4);
        float vv[8] = {va.x, va.y, va.z, va.w, vb.x, vb.y, vb.z, vb.w};
#pragma unroll
        for (int j = 0; j < 8; j++) {
            short hi, lo;
            split_bf(vv[j], hi, lo);
            ahi[kc][j] = hi;
            alo[kc][j] = lo;
        }
    }
    f32x4 acc[8];
#pragma unroll
    for (int c = 0; c < 8; c++) acc[c] = (f32x4){0.f, 0.f, 0.f, 0.f};

    char* ldst = (char*)Bs + wv * 8192;
    const char* g1 = (const char*)Whi + wv * 8192 + lane * 16;
#pragma unroll
    for (int cc = 0; cc < 8; cc++) gload_lds16(g1 + cc * 1024, ldst + cc * 1024);
    __syncthreads();
#pragma unroll
    for (int kc = 0; kc < 4; kc++)
#pragma unroll
        for (int c = 0; c < 8; c++) {
            int o = c * 16 + lm;
            bf16x8 bfr = *(const bf16x8*)&Bs[o * 128 + (((kc * 4 + quad) ^ (o & 7)) << 3)];
            acc[c] = __builtin_amdgcn_mfma_f32_16x16x32_bf16(ahi[kc], bfr, acc[c], 0, 0, 0);
            acc[c] = __builtin_amdgcn_mfma_f32_16x16x32_bf16(alo[kc], bfr, acc[c], 0, 0, 0);
        }
    __syncthreads();
    const char* g2 = (const char*)Wlo + wv * 8192 + lane * 16;
#pragma unroll
    for (int cc = 0; cc < 8; cc++) gload_lds16(g2 + cc * 1024, ldst + cc * 1024);
    __syncthreads();
#pragma unroll
    for (int kc = 0; kc < 4; kc++)
#pragma unroll
        for (int c = 0; c < 8; c++) {
            int o = c * 16 + lm;
            bf16x8 bfr = *(const bf16x8*)&Bs[o * 128 + (((kc * 4 + quad) ^ (o & 7)) << 3)];
            acc[c] = __builtin_amdgcn_mfma_f32_16x16x32_bf16(ahi[kc], bfr, acc[c], 0, 0, 0);
        }
    int orow = row0 + wv * 16 + quad * 4;
#pragma unroll
    for (int c = 0; c < 8; c++) {
        int col = c * 16 + lm;
        float bi = b[col];
#pragma unroll
        for (int v = 0; v < 4; v++)
            h[(orow + v) * H + col] = fmaxf(acc[c][v] + bi, 0.0f);
    }
}

// ------- fused BN+residual + memberships + rule-mix GEMM (BM=64) -----------
// Double-buffered B staging: one barrier per rule; rule r+1 staged while
// computing rule r. hs prologue overlays the 64 KB dbuf region.
__global__ __launch_bounds__(256, 2) void k_gemm3(
    const float* __restrict__ h, const float* __restrict__ aprev,
    const float* __restrict__ sums, const float* __restrict__ gamma,
    const float* __restrict__ beta, const short* __restrict__ BT,
    const float* __restrict__ bc, const float* __restrict__ cen,
    const float* __restrict__ iw, unsigned short* __restrict__ msgb,
    float* __restrict__ hout) {
    __shared__ __align__(16) char smem[65536];  // Bs[2][16384] shorts; hs overlay
    float(*hs)[132] = (float(*)[132])smem;      // 33792 B, prologue only
    __shared__ float wsh[16][64];
    __shared__ float sm[64][17];

    int tid = threadIdx.x, lane = tid & 63, wv = tid >> 6;
    int quad = lane >> 4, lm = lane & 15;
    int row0 = blockIdx.x * 64;

    // stage h tile (64x128 f32); BN+residual fusion when gamma != null
    if (gamma) {
        for (int g = tid; g < 2048; g += 256) {
            int rr = g >> 5, cc = (g & 31) << 2;
            int grow = row0 + rr;
            f32x4 hv = *(const f32x4*)&h[grow * H + cc];
            f32x4 av = *(const f32x4*)&aprev[grow * H + cc];
            f32x4 r = bn4(hv, av, *(const f32x4*)&sums[cc],
                          *(const f32x4*)&sums[H + cc],
                          *(const f32x4*)&gamma[cc], *(const f32x4*)&beta[cc]);
            *(f32x4*)&hs[rr][cc] = r;
            *(f32x4*)&hout[grow * H + cc] = r;
        }
    } else {
        const f32x4* hg = (const f32x4*)(h + row0 * H);
        for (int g = tid; g < 2048; g += 256) {
            int rr = g >> 5, cc = (g & 31) << 2;
            *(f32x4*)&hs[rr][cc] = hg[g];
        }
    }
    __syncthreads();

    // membership partial scores: wave wv -> rules wv*4..+3, lane = row
    {
        int wvu = __builtin_amdgcn_readfirstlane(wv);
        const float* c0 = cen + (wvu * 4 + 0) * H;
        const float* c1 = cen + (wvu * 4 + 1) * H;
        const float* c2 = cen + (wvu * 4 + 2) * H;
        const float* c3 = cen + (wvu * 4 + 3) * H;
        const float* w0 = iw + (wvu * 4 + 0) * H;
        const float* w1 = iw + (wvu * 4 + 1) * H;
        const float* w2 = iw + (wvu * 4 + 2) * H;
        const float* w3 = iw + (wvu * 4 + 3) * H;
        float s0 = 0.f, s1 = 0.f, s2 = 0.f, s3 = 0.f;
#pragma unroll 4
        for (int j0 = 0; j0 < H; j0 += 4) {
            f32x4 hv = *(const f32x4*)&hs[lane][j0];
            f32x4 cv, wv4, d;
            cv = *(const f32x4*)(c0 + j0); wv4 = *(const f32x4*)(w0 + j0);
            d = hv - cv;
            s0 += d.x * d.x * wv4.x + d.y * d.y * wv4.y + d.z * d.z * wv4.z + d.w * d.w * wv4.w;
            cv = *(const f32x4*)(c1 + j0); wv4 = *(const f32x4*)(w1 + j0);
            d = hv - cv;
            s1 += d.x * d.x * wv4.x + d.y * d.y * wv4.y + d.z * d.z * wv4.z + d.w * d.w * wv4.w;
            cv = *(const f32x4*)(c2 + j0); wv4 = *(const f32x4*)(w2 + j0);
            d = hv - cv;
            s2 += d.x * d.x * wv4.x + d.y * d.y * wv4.y + d.z * d.z * wv4.z + d.w * d.w * wv4.w;
            cv = *(const f32x4*)(c3 + j0); wv4 = *(const f32x4*)(w3 + j0);
            d = hv - cv;
            s3 += d.x * d.x * wv4.x + d.y * d.y * wv4.y + d.z * d.z * wv4.z + d.w * d.w * wv4.w;
        }
        sm[lane][wvu * 4 + 0] = s0;
        sm[lane][wvu * 4 + 1] = s1;
        sm[lane][wvu * 4 + 2] = s2;
        sm[lane][wvu * 4 + 3] = s3;
    }

    // extract this lane's A-row fragments (hi/lo split), from LDS
    bf16x8 ahi[4], alo[4];
    {
        int m = wv * 16 + lm;
#pragma unroll
        for (int kc = 0; kc < 4; kc++) {
            f32x4 va = *(const f32x4*)&hs[m][kc * 32 + quad * 8];
            f32x4 vb = *(const f32x4*)&hs[m][kc * 32 + quad * 8 + 4];
            float vv[8] = {va.x, va.y, va.z, va.w, vb.x, vb.y, vb.z, vb.w};
#pragma unroll
            for (int j = 0; j < 8; j++) {
                short hi, lo;
                split_bf(vv[j], hi, lo);
                ahi[kc][j] = hi;
                alo[kc][j] = lo;
            }
        }
    }
    __syncthreads();  // hs consumers done -> dbuf region free

    // softmax over 16 rules per row -> wsh[r][row]
    if (tid < 64) {
        float v[16], mx = -1e30f;
#pragma unroll
        for (int r = 0; r < R; r++) {
            v[r] = -sm[tid][r];
            mx = fmaxf(mx, v[r]);
        }
        float sum = 0.f, e[16];
#pragma unroll
        for (int r = 0; r < R; r++) {
            e[r] = __expf(v[r] - mx);
            sum += e[r];
        }
        float inv = 1.0f / sum;
#pragma unroll
        for (int r = 0; r < R; r++) wsh[r][tid] = e[r] * inv;
    }

    // prologue: stage rule 0 into half 0
    {
        const char* gsrc = (const char*)BT + wv * 8192 + lane * 16;
        char* ld = smem + wv * 8192;
#pragma unroll
        for (int cc = 0; cc < 8; cc++) gload_lds16(gsrc + cc * 1024, ld + cc * 1024);
    }
    __syncthreads();  // wsh visible + rule0 staged

    f32x4 out[8];
#pragma unroll
    for (int c = 0; c < 8; c++) out[c] = (f32x4){0.f, 0.f, 0.f, 0.f};

    for (int r = 0; r < R; r++) {
        // prefetch rule r+1 into the other half (async, overlaps compute)
        if (r + 1 < R) {
            const char* gsrc = (const char*)(BT + (r + 1) * 16384) + wv * 8192 + lane * 16;
            char* ld = smem + ((r + 1) & 1) * 32768 + wv * 8192;
#pragma unroll
            for (int cc = 0; cc < 8; cc++)
                gload_lds16(gsrc + cc * 1024, ld + cc * 1024);
        }
        const short* Bcur = (const short*)(smem + (r & 1) * 32768);

        f32x4 accr[8];
#pragma unroll
        for (int c = 0; c < 8; c++) accr[c] = (f32x4){0.f, 0.f, 0.f, 0.f};
#pragma unroll
        for (int kc = 0; kc < 4; kc++)
#pragma unroll
            for (int c = 0; c < 8; c++) {
                int o = c * 16 + lm;
                bf16x8 bfr = *(const bf16x8*)&Bcur[o * 128 + (((kc * 4 + quad) ^ (o & 7)) << 3)];
                accr[c] = __builtin_amdgcn_mfma_f32_16x16x32_bf16(ahi[kc], bfr, accr[c], 0, 0, 0);
                accr[c] = __builtin_amdgcn_mfma_f32_16x16x32_bf16(alo[kc], bfr, accr[c], 0, 0, 0);
            }
        f32x4 wr4 = *(const f32x4*)&wsh[r][wv * 16 + quad * 4];
#pragma unroll
        for (int c = 0; c < 8; c++) {
            out[c].x += wr4.x * accr[c].x;
            out[c].y += wr4.y * accr[c].y;
            out[c].z += wr4.z * accr[c].z;
            out[c].w += wr4.w * accr[c].w;
        }
        __syncthreads();  // drains prefetch vmcnt + syncs consumers
    }

    // bias via one K=32 MFMA: A = w (k<16 else 0), B = bc (staged into half 0)
    short* Bs0 = (short*)smem;
    for (int g = tid; g < 512; g += 256) {
        int o = g >> 2, kb = g & 3;
        bf16x8 v;
#pragma unroll
        for (int j = 0; j < 8; j++) {
            int k = kb * 8 + j;
            v[j] = (k < R) ? f2bf_rne(bc[k * H + o]) : (short)0;
        }
        *(bf16x8*)&Bs0[o * 128 + ((kb ^ (o & 7)) << 3)] = v;
    }
    bf16x8 abias;
#pragma unroll
    for (int j = 0; j < 8; j++)
        abias[j] = (quad < 2) ? f2bf_rne(wsh[quad * 8 + j][wv * 16 + lm]) : (short)0;
    __syncthreads();
#pragma unroll
    for (int c = 0; c < 8; c++) {
        int o = c * 16 + lm;
        bf16x8 bfr = *(const bf16x8*)&Bs0[o * 128 + ((quad ^ (o & 7)) << 3)];
        out[c] = __builtin_amdgcn_mfma_f32_16x16x32_bf16(abias, bfr, out[c], 0, 0, 0);
    }

    // store msg as bf16
    int orow = row0 + wv * 16 + quad * 4;
#pragma unroll
    for (int c = 0; c < 8; c++) {
        int col = c * 16 + lm;
#pragma unroll
        for (int v = 0; v < 4; v++)
            msgb[(orow + v) * H + col] = (unsigned short)f2bf_rne(out[c][v]);
    }
}

// ---------------- CSR aggregate (8-deep ILP, no epilogue) ----------------
__global__ __launch_bounds__(256) void k_agg(
    const unsigned short* __restrict__ msgb, const int* __restrict__ row_start,
    const int* __restrict__ esrc, float* __restrict__ a) {
    int tid = threadIdx.x;
    int g = tid >> 5, lane = tid & 31;
    int n = blockIdx.x * 8 + g;
    int b = row_start[n], e = row_start[n + 1];
    f32x4 a0 = {0.f, 0.f, 0.f, 0.f}, a1 = a0, a2 = a0, a3 = a0;
    f32x4 a4 = a0, a5 = a0, a6 = a0, a7 = a0;
    int i = b;
    for (; i + 8 <= e; i += 8) {
        int s0 = esrc[i], s1 = esrc[i + 1], s2 = esrc[i + 2], s3 = esrc[i + 3];
        int s4 = esrc[i + 4], s5 = esrc[i + 5], s6 = esrc[i + 6], s7 = esrc[i + 7];
        a0 += bf4f(*(const u16x4*)&msgb[s0 * H + lane * 4]);
        a1 += bf4f(*(const u16x4*)&msgb[s1 * H + lane * 4]);
        a2 += bf4f(*(const u16x4*)&msgb[s2 * H + lane * 4]);
        a3 += bf4f(*(const u16x4*)&msgb[s3 * H + lane * 4]);
        a4 += bf4f(*(const u16x4*)&msgb[s4 * H + lane * 4]);
        a5 += bf4f(*(const u16x4*)&msgb[s5 * H + lane * 4]);
        a6 += bf4f(*(const u16x4*)&msgb[s6 * H + lane * 4]);
        a7 += bf4f(*(const u16x4*)&msgb[s7 * H + lane * 4]);
    }
    for (; i < e; i++)
        a0 += bf4f(*(const u16x4*)&msgb[esrc[i] * H + lane * 4]);
    f32x4 t = ((a0 + a1) + (a2 + a3)) + ((a4 + a5) + (a6 + a7));
    float id = 1.0f / fmaxf((float)(e - b), 1.0f);
    f32x4 res;
    res.x = fmaxf(t.x * id, 0.f);
    res.y = fmaxf(t.y * id, 0.f);
    res.z = fmaxf(t.z * id, 0.f);
    res.w = fmaxf(t.w * id, 0.f);
    *(f32x4*)&a[n * H + lane * 4] = res;
}

// ---------------- BatchNorm stats (separate; shallow atomic chains) --------
__global__ __launch_bounds__(128) void k_bnstats(const float* __restrict__ a,
                                                 float* __restrict__ sums) {
    int t = threadIdx.x;
    float s = 0.0f, s2 = 0.0f;
    for (int n = blockIdx.x; n < NN; n += gridDim.x) {
        float v = a[n * H + t];
        s += v;
        s2 += v * v;
    }
    atomicAdd(&sums[t], s);
    atomicAdd(&sums[H + t], s2);
}

// ---------------- head: fused BN+residual -> MFMA -> softmax ----------------
__global__ __launch_bounds__(256, 2) void k_head2(
    const float* __restrict__ h, const float* __restrict__ aprev,
    const float* __restrict__ sums, const float* __restrict__ gamma,
    const float* __restrict__ beta, const short* __restrict__ Whi,
    const short* __restrict__ Wlo, const float* __restrict__ bh,
    float* __restrict__ out) {
    __shared__ short Bs[12288];  // hi: shorts [0,6144), lo: shorts [6144,12288)
    int tid = threadIdx.x, lane = tid & 63, wv = tid >> 6;
    int quad = lane >> 4, lm = lane & 15;
    int row0 = blockIdx.x * 64;
    int m = row0 + wv * 16 + lm;

    bf16x8 ahi[4], alo[4];
#pragma unroll
    for (int kc = 0; kc < 4; kc++) {
        int base = kc * 32 + quad * 8;
        f32x4 hv0 = *(const f32x4*)&h[m * H + base];
        f32x4 hv1 = *(const f32x4*)&h[m * H + base + 4];
        f32x4 av0 = *(const f32x4*)&aprev[m * H + base];
        f32x4 av1 = *(const f32x4*)&aprev[m * H + base + 4];
        f32x4 r0 = bn4(hv0, av0, *(const f32x4*)&sums[base],
                       *(const f32x4*)&sums[H + base],
                       *(const f32x4*)&gamma[base], *(const f32x4*)&beta[base]);
        f32x4 r1 = bn4(hv1, av1, *(const f32x4*)&sums[base + 4],
                       *(const f32x4*)&sums[H + base + 4],
                       *(const f32x4*)&gamma[base + 4],
                       *(const f32x4*)&beta[base + 4]);
        float vv[8] = {r0.x, r0.y, r0.z, r0.w, r1.x, r1.y, r1.z, r1.w};
#pragma unroll
        for (int j = 0; j < 8; j++) {
            short hi, lo;
            split_bf(vv[j], hi, lo);
            ahi[kc][j] = hi;
            alo[kc][j] = lo;
        }
    }
    {
        char* ldst = (char*)Bs + wv * 3072;
        const char* g1 = (const char*)Whi + wv * 3072 + lane * 16;
        const char* g2 = (const char*)Wlo + wv * 3072 + lane * 16;
#pragma unroll
        for (int cc = 0; cc < 3; cc++) gload_lds16(g1 + cc * 1024, ldst + cc * 1024);
        char* ldst2 = (char*)Bs + 12288 + wv * 3072;  // byte offset of lo half
#pragma unroll
        for (int cc = 0; cc < 3; cc++) gload_lds16(g2 + cc * 1024, ldst2 + cc * 1024);
    }
    __syncthreads();
    f32x4 acc[3];
#pragma unroll
    for (int c = 0; c < 3; c++) acc[c] = (f32x4){0.f, 0.f, 0.f, 0.f};
#pragma unroll
    for (int kc = 0; kc < 4; kc++)
#pragma unroll
        for (int c = 0; c < 3; c++) {
            int o = c * 16 + lm;
            int off = o * 128 + (((kc * 4 + quad) ^ (o & 7)) << 3);
            bf16x8 bH = *(const bf16x8*)&Bs[off];
            bf16x8 bL = *(const bf16x8*)&Bs[6144 + off];
            acc[c] = __builtin_amdgcn_mfma_f32_16x16x32_bf16(ahi[kc], bH, acc[c], 0, 0, 0);
            acc[c] = __builtin_amdgcn_mfma_f32_16x16x32_bf16(alo[kc], bH, acc[c], 0, 0, 0);
            acc[c] = __builtin_amdgcn_mfma_f32_16x16x32_bf16(ahi[kc], bL, acc[c], 0, 0, 0);
        }
    float bh0 = bh[lm], bh1 = bh[16 + lm];
    float bh2 = (lm < 8) ? bh[32 + lm] : 0.f;
    int orow = row0 + wv * 16 + quad * 4;
#pragma unroll
    for (int v = 0; v < 4; v++) {
        float v0 = acc[0][v] + bh0;
        float v1 = acc[1][v] + bh1;
        float v2 = (lm < 8) ? (acc[2][v] + bh2) : -1e30f;
        float mx = fmaxf(fmaxf(v0, v1), v2);
        for (int off = 8; off; off >>= 1) mx = fmaxf(mx, __shfl_xor(mx, off, 16));
        float e0 = __expf(v0 - mx), e1 = __expf(v1 - mx);
        float e2 = (lm < 8) ? __expf(v2 - mx) : 0.f;
        float s = e0 + e1 + e2;
        for (int off = 8; off; off >>= 1) s += __shfl_xor(s, off, 16);
        float inv = 1.0f / s;
        out[(orow + v) * ODIM + lm] = e0 * inv;
        out[(orow + v) * ODIM + 16 + lm] = e1 * inv;
        if (lm < 8) out[(orow + v) * ODIM + 32 + lm] = e2 * inv;
    }
}

extern "C" void kernel_launch(void* const* d_in, const int* in_sizes, int n_in,
                              void* d_out, int out_size, void* d_ws, size_t ws_size,
                              hipStream_t stream) {
    const float* x = (const float*)d_in[0];
    const int* edge_index = (const int*)d_in[1];
    const float* W_in = (const float*)d_in[2];
    const float* b_in = (const float*)d_in[3];
    const float* centers = (const float*)d_in[4];
    const float* widths = (const float*)d_in[5];
    const float* Wc = (const float*)d_in[6];
    const float* bc = (const float*)d_in[7];
    const float* bn_gamma = (const float*)d_in[8];
    const float* bn_beta = (const float*)d_in[9];
    const float* W_head = (const float*)d_in[10];
    const float* b_head = (const float*)d_in[11];
    float* out = (float*)d_out;

    const int* src = edge_index;
    const int* dst = edge_index + NE;

    // workspace layout
    float* h = (float*)d_ws;
    float* a = h + NN * H;
    float* sumsAll = a + NN * H;      // 3 x 256
    float* IW = sumsAll + 768;        // NL*R*H
    int* binCnt = (int*)(IW + NL * R * H);  // 64
    int* binStart = binCnt + NBIN;    // 65
    int* row_start = binStart + NBIN + 1;   // NN+1
    int* pbuf = row_start + NN + 1;   // NBIN*BINCAP
    int* esrc = pbuf + NBIN * BINCAP; // NE
    uintptr_t p = (uintptr_t)(esrc + NE);
    p = (p + 63) & ~(uintptr_t)63;
    unsigned short* msgb = (unsigned short*)p;  // NN*H bf16
    short* WcT = (short*)(msgb + NN * H);       // NL*R*H*H
    short* WinHi = WcT + NL * R * H * H;        // 16384
    short* WinLo = WinHi + 16384;
    short* WhHi = WinLo + 16384;                // 6144
    short* WhLo = WhHi + 6144;

    k_prep_all<<<3185, 256, 0, stream>>>(Wc, WcT, W_in, WinHi, WinLo, W_head,
                                         WhHi, WhLo, widths, IW, binCnt);
    k_part<<<NE / 8192, 256, 0, stream>>>(src, dst, binCnt, pbuf);
    k_scan64<<<1, 64, 0, stream>>>(binCnt, binStart, row_start, sumsAll);
    k_sortp<<<NBIN, 512, 0, stream>>>(binCnt, binStart, pbuf, esrc, row_start);

    k_in_mfma<<<NN / 64, 256, 0, stream>>>(x, WinHi, WinLo, b_in, h);

    for (int l = 0; l < NL; l++) {
        const float* gm = (l == 0) ? nullptr : bn_gamma + (l - 1) * H;
        const float* bt = (l == 0) ? nullptr : bn_beta + (l - 1) * H;
        const float* sm = (l == 0) ? nullptr : sumsAll + 256 * (l - 1);
        k_gemm3<<<NN / 64, 256, 0, stream>>>(h, a, sm, gm, bt,
                                             WcT + l * R * H * H, bc + l * R * H,
                                             centers + l * R * H, IW + l * R * H,
                                             msgb, h);
        k_agg<<<NN / 8, 256, 0, stream>>>(msgb, row_start, esrc, a);
        k_bnstats<<<512, 128, 0, stream>>>(a, sumsAll + 256 * l);
    }
    k_head2<<<NN / 64, 256, 0, stream>>>(h, a, sumsAll + 512, bn_gamma + 2 * H,
                                         bn_beta + 2 * H, WhHi, WhLo, b_head, out);
}